// Round 2
// baseline (667.814 us; speedup 1.0000x reference)
//
#include <hip/hip_runtime.h>
#include <cstdint>
#include <cstddef>

typedef __attribute__((ext_vector_type(8))) __bf16   bf16x8;
typedef __attribute__((ext_vector_type(2))) __bf16   bf16x2;
typedef __attribute__((ext_vector_type(4))) float    f32x4;
typedef __attribute__((ext_vector_type(4))) uint32_t u32x4;

#define N_ROWS   1179648   // 8*384*384
#define N_TILES  73728     // N_ROWS/16
#define BLOCKS   2304      // 8 waves each -> 18432 waves -> 4 tiles/wave
#define SDIM     384
#define VOCAB    5

// tanh-form GELU: x * sigmoid(x*(c1 + c2*x^2)*(-?)) ... derived:
// gelu(x) ~= x / (1 + exp2(x*(c1 + c2*x^2)))
// c1 = -2*log2(e)*sqrt(2/pi), c2 = c1*0.044715.  |err vs exact| <= ~3e-4
__device__ __forceinline__ float gelu_fast(float x){
  float u = x * x;
  float w = __builtin_fmaf(-0.10294456f, u, -2.3021255f);
  float e = __builtin_amdgcn_exp2f(x * w);
  return x * __builtin_amdgcn_rcpf(e + 1.0f);
}

__device__ __forceinline__ bf16x8 mk_bf8(f32x4 a, f32x4 b){
  bf16x8 v;
  v[0]=(__bf16)a[0]; v[1]=(__bf16)a[1]; v[2]=(__bf16)a[2]; v[3]=(__bf16)a[3];
  v[4]=(__bf16)b[0]; v[5]=(__bf16)b[1]; v[6]=(__bf16)b[2]; v[7]=(__bf16)b[3];
  return v;
}

__global__ __launch_bounds__(512, 6)
void mlp_kernel(const float* __restrict__ x,
                const float* __restrict__ W1, const float* __restrict__ b1,
                const float* __restrict__ W2, const float* __restrict__ b2,
                const float* __restrict__ W3, const float* __restrict__ b3,
                const float* __restrict__ lng, const float* __restrict__ lnb,
                const float* __restrict__ Wo,  const float* __restrict__ bo,
                float* __restrict__ tmp)
{
  // W1..W3 as bf16 [m][k] (8KB each) + Wo^T padded [16][64] (2KB), XOR-swizzled rows
  __shared__ __align__(16) uint8_t  Wl[26624];
  __shared__ __align__(16) uint32_t bounce[8][512];   // per-wave 2KB scratch

  const int tid = threadIdx.x;

  // ---- stage weights: global fp32 -> LDS bf16, [m][k], swizzle byte^=((m&7)<<4) ----
  {
    int m = tid & 63, g = tid >> 6;
    #pragma unroll 1
    for (int idx = g; idx < 96; idx += 8) {        // idx = L*32 + kp
      int L = idx >> 5, kp = idx & 31;
      const float* W = (L == 0) ? W1 : ((L == 1) ? W2 : W3);
      float lo = W[(2 * kp    ) * 64 + m];
      float hi = W[(2 * kp + 1) * 64 + m];
      bf16x2 p = { (__bf16)lo, (__bf16)hi };
      *(uint32_t*)(Wl + L * 8192 + m * 128 + ((4 * kp) ^ ((m & 7) << 4))) =
          __builtin_bit_cast(uint32_t, p);
    }
    int mm = tid & 15, kp = tid >> 4;              // Wo^T: rows m=0..15 (>=5 zero)
    float lo = (mm < VOCAB) ? Wo[(2 * kp    ) * VOCAB + mm] : 0.0f;
    float hi = (mm < VOCAB) ? Wo[(2 * kp + 1) * VOCAB + mm] : 0.0f;
    bf16x2 p = { (__bf16)lo, (__bf16)hi };
    *(uint32_t*)(Wl + 24576 + mm * 128 + ((4 * kp) ^ ((mm & 7) << 4))) =
        __builtin_bit_cast(uint32_t, p);
  }
  __syncthreads();

  const int wav  = tid >> 6, lane = tid & 63;
  const int h    = lane >> 4;            // feature sub-block / k selector
  const int b    = lane & 15;            // batch-row within 16-row tile
  const int swzW = (b & 7) << 4;         // byte XOR for W-row reads (m&7 == b&7)
  const int swzD = (b & 7) << 2;         // dword XOR for bounce buffer
  const int rowB = b * 128;              // W row byte offset
  const int kOff = 16 * h;               // byte of k=8h (bf16)
  uint32_t* myB = bounce[wav];
  float*    myF = (float*)bounce[wav];

  const int gw = blockIdx.x * 8 + wav;
  const int t0 = gw * 4;

  for (int t = t0; t < t0 + 4; ++t) {
    const int row0 = t * 16;

    // ---- load x tile -> B fragments (x^T), native bf16 casts ----
    u32x4 bfr[2];
    {
      const float* px = x + (size_t)(row0 + b) * 64 + 8 * h;
      f32x4 a0 = *(const f32x4*)(px);
      f32x4 a1 = *(const f32x4*)(px + 4);
      f32x4 a2 = *(const f32x4*)(px + 32);
      f32x4 a3 = *(const f32x4*)(px + 36);
      bfr[0] = __builtin_bit_cast(u32x4, mk_bf8(a0, a1));
      bfr[1] = __builtin_bit_cast(u32x4, mk_bf8(a2, a3));
    }

    // ---- three (Linear -> gelu -> LN) blocks ----
    #pragma unroll
    for (int L = 0; L < 3; ++L) {
      const float* bias = (L == 0) ? b1 : ((L == 1) ? b2 : b3);
      const uint8_t* wp = Wl + L * 8192 + rowB;
      f32x4 acc[4];
      #pragma unroll
      for (int mt = 0; mt < 4; ++mt) {
        u32x4 w0 = *(const u32x4*)(wp + mt * 2048 + ((kOff     ) ^ swzW));
        u32x4 w1 = *(const u32x4*)(wp + mt * 2048 + ((kOff + 64) ^ swzW));
        acc[mt] = *(const f32x4*)(bias + 16 * mt + 4 * h);
        acc[mt] = __builtin_amdgcn_mfma_f32_16x16x32_bf16(
            __builtin_bit_cast(bf16x8, w0), __builtin_bit_cast(bf16x8, bfr[0]),
            acc[mt], 0, 0, 0);
        acc[mt] = __builtin_amdgcn_mfma_f32_16x16x32_bf16(
            __builtin_bit_cast(bf16x8, w1), __builtin_bit_cast(bf16x8, bfr[1]),
            acc[mt], 0, 0, 0);
      }

      #pragma unroll
      for (int mt = 0; mt < 4; ++mt)
        #pragma unroll
        for (int r = 0; r < 4; ++r)
          acc[mt][r] = gelu_fast(acc[mt][r]);

      // LayerNorm over 64 feats of row b (lanes b, b+16, b+32, b+48)
      float s1 = 0.0f, s2 = 0.0f;
      #pragma unroll
      for (int mt = 0; mt < 4; ++mt)
        #pragma unroll
        for (int r = 0; r < 4; ++r) {
          float v = acc[mt][r];
          s1 += v;
          s2 = __builtin_fmaf(v, v, s2);
        }
      s1 += __shfl_xor(s1, 16); s2 += __shfl_xor(s2, 16);
      s1 += __shfl_xor(s1, 32); s2 += __shfl_xor(s2, 32);
      float mu   = s1 * (1.0f / 64.0f);
      float var  = __builtin_fmaf(s2, (1.0f / 64.0f), -mu * mu);
      float rstd = rsqrtf(var + 1e-5f);
      float nm   = -mu * rstd;

      // normalize + affine -> bf16 -> swizzled per-wave LDS bounce -> next B frags
      #pragma unroll
      for (int mt = 0; mt < 4; ++mt) {
        f32x4 gg = *(const f32x4*)(lng + 16 * mt + 4 * h);
        f32x4 bb = *(const f32x4*)(lnb + 16 * mt + 4 * h);
        float n0 = __builtin_fmaf(__builtin_fmaf(acc[mt][0], rstd, nm), gg[0], bb[0]);
        float n1 = __builtin_fmaf(__builtin_fmaf(acc[mt][1], rstd, nm), gg[1], bb[1]);
        float n2 = __builtin_fmaf(__builtin_fmaf(acc[mt][2], rstd, nm), gg[2], bb[2]);
        float n3 = __builtin_fmaf(__builtin_fmaf(acc[mt][3], rstd, nm), gg[3], bb[3]);
        bf16x2 p0 = { (__bf16)n0, (__bf16)n1 };
        bf16x2 p1 = { (__bf16)n2, (__bf16)n3 };
        int di = (b * 32 + 8 * mt + 2 * h) ^ swzD;
        myB[di]     = __builtin_bit_cast(uint32_t, p0);
        myB[di + 1] = __builtin_bit_cast(uint32_t, p1);
      }
      #pragma unroll
      for (int s = 0; s < 2; ++s)
        bfr[s] = *(const u32x4*)(myB + ((b * 32 + 16 * s + 4 * h) ^ swzD));
    }

    // ---- output projection out^T = Wo^T . h3^T + bo ----
    f32x4 ao;
    #pragma unroll
    for (int r = 0; r < 4; ++r) {
      int v = 4 * h + r;
      ao[r] = (v < VOCAB) ? bo[v] : 0.0f;
    }
    {
      const uint8_t* wp = Wl + 24576 + rowB;
      u32x4 w0 = *(const u32x4*)(wp + ((kOff     ) ^ swzW));
      u32x4 w1 = *(const u32x4*)(wp + ((kOff + 64) ^ swzW));
      ao = __builtin_amdgcn_mfma_f32_16x16x32_bf16(
          __builtin_bit_cast(bf16x8, w0), __builtin_bit_cast(bf16x8, bfr[0]),
          ao, 0, 0, 0);
      ao = __builtin_amdgcn_mfma_f32_16x16x32_bf16(
          __builtin_bit_cast(bf16x8, w1), __builtin_bit_cast(bf16x8, bfr[1]),
          ao, 0, 0, 0);
    }

    // gather 16*5 floats in LDS, store 320B coalesced
    #pragma unroll
    for (int r = 0; r < 4; ++r) {
      int v = 4 * h + r;
      if (v < VOCAB) myF[b * VOCAB + v] = ao[r];
    }
    float* dst = tmp + (size_t)row0 * VOCAB;
    dst[lane] = myF[lane];
    if (lane < 16) dst[64 + lane] = myF[64 + lane];
  }
}

// symmetrize: out[b,i,j,:] = 0.5*(tmp[b,i,j,:] + tmp[b,j,i,:]), LDS tile transpose
__global__ __launch_bounds__(256)
void sym_kernel(const float* __restrict__ tmp, float* __restrict__ out)
{
  __shared__ float A[32][164];
  __shared__ float B[32][164];
  int bid = blockIdx.x;
  int bb = bid / 144, r2 = bid - bb * 144;
  int ti = r2 / 12,  tj = r2 - ti * 12;
  int i0 = ti * 32,  j0 = tj * 32;
  const size_t base = (size_t)bb * SDIM * SDIM;

  for (int idx = threadIdx.x; idx < 32 * 160; idx += 256) {
    int r = idx / 160, c = idx - r * 160;
    A[r][c] = tmp[(base + (size_t)(i0 + r) * SDIM + j0) * VOCAB + c];
    B[r][c] = tmp[(base + (size_t)(j0 + r) * SDIM + i0) * VOCAB + c];
  }
  __syncthreads();
  for (int idx = threadIdx.x; idx < 32 * 160; idx += 256) {
    int r = idx / 160, c = idx - r * 160;
    int jc = c / 5, v = c - jc * 5;
    out[(base + (size_t)(i0 + r) * SDIM + j0) * VOCAB + c] =
        0.5f * (A[r][c] + B[jc][r * 5 + v]);
  }
}

extern "C" void kernel_launch(void* const* d_in, const int* in_sizes, int n_in,
                              void* d_out, int out_size, void* d_ws, size_t ws_size,
                              hipStream_t stream)
{
  const float* x   = (const float*)d_in[0];
  const float* W1  = (const float*)d_in[1];
  const float* b1  = (const float*)d_in[2];
  const float* W2  = (const float*)d_in[3];
  const float* b2  = (const float*)d_in[4];
  const float* W3  = (const float*)d_in[5];
  const float* b3  = (const float*)d_in[6];
  const float* lng = (const float*)d_in[7];
  const float* lnb = (const float*)d_in[8];
  const float* Wo  = (const float*)d_in[9];
  const float* bo  = (const float*)d_in[10];

  float* tmp = (float*)d_ws;   // 23.6 MB scratch
  float* out = (float*)d_out;

  mlp_kernel<<<BLOCKS, 512, 0, stream>>>(x, W1, b1, W2, b2, W3, b3,
                                         lng, lnb, Wo, bo, tmp);
  sym_kernel<<<8 * 12 * 12, 256, 0, stream>>>(tmp, out);
}

// Round 3
// 204.341 us; speedup vs baseline: 3.2681x; 3.2681x over previous
//
#include <hip/hip_runtime.h>
#include <cstdint>
#include <cstddef>

typedef __attribute__((ext_vector_type(8))) __bf16   bf16x8;
typedef __attribute__((ext_vector_type(2))) __bf16   bf16x2;
typedef __attribute__((ext_vector_type(4))) float    f32x4;
typedef __attribute__((ext_vector_type(4))) uint32_t u32x4;

#define N_ROWS   1179648   // 8*384*384
#define N_TILES  73728     // N_ROWS/16
#define BLOCKS   2304      // 8 waves each -> 18432 waves -> 4 tiles/wave
#define SDIM     384
#define VOCAB    5

// tanh-form GELU via exp2+rcp: gelu(x) ~= x / (1 + exp2(x*(c1 + c2*x^2)))
// c1 = -2*log2(e)*sqrt(2/pi), c2 = c1*0.044715. |err vs exact| <= ~4e-4
__device__ __forceinline__ float gelu_fast(float x){
  float u = x * x;
  float w = __builtin_fmaf(-0.10294456f, u, -2.3021255f);
  float e = __builtin_amdgcn_exp2f(x * w);
  return x * __builtin_amdgcn_rcpf(e + 1.0f);
}

__device__ __forceinline__ bf16x8 mk_bf8(f32x4 a, f32x4 b){
  bf16x8 v;
  v[0]=(__bf16)a[0]; v[1]=(__bf16)a[1]; v[2]=(__bf16)a[2]; v[3]=(__bf16)a[3];
  v[4]=(__bf16)b[0]; v[5]=(__bf16)b[1]; v[6]=(__bf16)b[2]; v[7]=(__bf16)b[3];
  return v;
}

__global__ __launch_bounds__(512)   // NO min-waves arg: R2's (512,6) forced VGPR=40 -> scratch spills (728MB writes)
void mlp_kernel(const float* __restrict__ x,
                const float* __restrict__ W1, const float* __restrict__ b1,
                const float* __restrict__ W2, const float* __restrict__ b2,
                const float* __restrict__ W3, const float* __restrict__ b3,
                const float* __restrict__ lng, const float* __restrict__ lnb,
                const float* __restrict__ Wo,  const float* __restrict__ bo,
                float* __restrict__ tmp)
{
  // W1..W3 as bf16 [m][k] (8KB each) + Wo^T padded [16][64] (2KB), XOR-swizzled rows
  __shared__ __align__(16) uint8_t  Wl[26624];
  __shared__ __align__(16) uint32_t bounce[8][512];   // per-wave 2KB scratch

  const int tid = threadIdx.x;

  // ---- stage weights: global fp32 -> LDS bf16, [m][k], swizzle byte^=((m&7)<<4) ----
  {
    int m = tid & 63, g = tid >> 6;
    #pragma unroll 1
    for (int idx = g; idx < 96; idx += 8) {        // idx = L*32 + kp
      int L = idx >> 5, kp = idx & 31;
      const float* W = (L == 0) ? W1 : ((L == 1) ? W2 : W3);
      float lo = W[(2 * kp    ) * 64 + m];
      float hi = W[(2 * kp + 1) * 64 + m];
      bf16x2 p = { (__bf16)lo, (__bf16)hi };
      *(uint32_t*)(Wl + L * 8192 + m * 128 + ((4 * kp) ^ ((m & 7) << 4))) =
          __builtin_bit_cast(uint32_t, p);
    }
    int mm = tid & 15, kp = tid >> 4;              // Wo^T: rows m=0..15 (>=5 zero)
    float lo = (mm < VOCAB) ? Wo[(2 * kp    ) * VOCAB + mm] : 0.0f;
    float hi = (mm < VOCAB) ? Wo[(2 * kp + 1) * VOCAB + mm] : 0.0f;
    bf16x2 p = { (__bf16)lo, (__bf16)hi };
    *(uint32_t*)(Wl + 24576 + mm * 128 + ((4 * kp) ^ ((mm & 7) << 4))) =
        __builtin_bit_cast(uint32_t, p);
  }
  __syncthreads();

  const int wav  = tid >> 6, lane = tid & 63;
  const int h    = lane >> 4;            // feature sub-block / k selector
  const int b    = lane & 15;            // batch-row within 16-row tile
  const int swzW = (b & 7) << 4;         // byte XOR for W-row reads (m&7 == b&7)
  const int swzD = (b & 7) << 2;         // dword XOR for bounce buffer
  const int rowB = b * 128;              // W row byte offset
  const int kOff = 16 * h;               // byte of k=8h (bf16)
  uint32_t* myB = bounce[wav];
  float*    myF = (float*)bounce[wav];

  // ---- hoist tile-invariant vectors into registers (kills per-tile global reads) ----
  f32x4 biasr[3][4], ggr[4], bbr[4], aoInit;
  #pragma unroll
  for (int mt = 0; mt < 4; ++mt) {
    biasr[0][mt] = *(const f32x4*)(b1  + 16 * mt + 4 * h);
    biasr[1][mt] = *(const f32x4*)(b2  + 16 * mt + 4 * h);
    biasr[2][mt] = *(const f32x4*)(b3  + 16 * mt + 4 * h);
    ggr[mt]      = *(const f32x4*)(lng + 16 * mt + 4 * h);
    bbr[mt]      = *(const f32x4*)(lnb + 16 * mt + 4 * h);
  }
  #pragma unroll
  for (int r = 0; r < 4; ++r) {
    int v = 4 * h + r;
    aoInit[r] = (v < VOCAB) ? bo[v] : 0.0f;
  }

  const int gw = blockIdx.x * 8 + wav;
  const int t0 = gw * 4;

  for (int t = t0; t < t0 + 4; ++t) {
    const int row0 = t * 16;

    // ---- load x tile -> B fragments (x^T), native bf16 casts ----
    u32x4 bfr[2];
    {
      const float* px = x + (size_t)(row0 + b) * 64 + 8 * h;
      f32x4 a0 = *(const f32x4*)(px);
      f32x4 a1 = *(const f32x4*)(px + 4);
      f32x4 a2 = *(const f32x4*)(px + 32);
      f32x4 a3 = *(const f32x4*)(px + 36);
      bfr[0] = __builtin_bit_cast(u32x4, mk_bf8(a0, a1));
      bfr[1] = __builtin_bit_cast(u32x4, mk_bf8(a2, a3));
    }

    // ---- three (Linear -> gelu -> LN) blocks ----
    #pragma unroll
    for (int L = 0; L < 3; ++L) {
      const uint8_t* wp = Wl + L * 8192 + rowB;
      f32x4 acc[4];
      #pragma unroll
      for (int mt = 0; mt < 4; ++mt) {
        u32x4 w0 = *(const u32x4*)(wp + mt * 2048 + ((kOff     ) ^ swzW));
        u32x4 w1 = *(const u32x4*)(wp + mt * 2048 + ((kOff + 64) ^ swzW));
        acc[mt] = biasr[L][mt];
        acc[mt] = __builtin_amdgcn_mfma_f32_16x16x32_bf16(
            __builtin_bit_cast(bf16x8, w0), __builtin_bit_cast(bf16x8, bfr[0]),
            acc[mt], 0, 0, 0);
        acc[mt] = __builtin_amdgcn_mfma_f32_16x16x32_bf16(
            __builtin_bit_cast(bf16x8, w1), __builtin_bit_cast(bf16x8, bfr[1]),
            acc[mt], 0, 0, 0);
      }

      #pragma unroll
      for (int mt = 0; mt < 4; ++mt)
        #pragma unroll
        for (int r = 0; r < 4; ++r)
          acc[mt][r] = gelu_fast(acc[mt][r]);

      // LayerNorm over 64 feats of row b (lanes b, b+16, b+32, b+48)
      float s1 = 0.0f, s2 = 0.0f;
      #pragma unroll
      for (int mt = 0; mt < 4; ++mt)
        #pragma unroll
        for (int r = 0; r < 4; ++r) {
          float v = acc[mt][r];
          s1 += v;
          s2 = __builtin_fmaf(v, v, s2);
        }
      s1 += __shfl_xor(s1, 16); s2 += __shfl_xor(s2, 16);
      s1 += __shfl_xor(s1, 32); s2 += __shfl_xor(s2, 32);
      float mu   = s1 * (1.0f / 64.0f);
      float var  = __builtin_fmaf(s2, (1.0f / 64.0f), -mu * mu);
      float rstd = rsqrtf(var + 1e-5f);
      float nm   = -mu * rstd;

      // normalize + affine -> bf16 -> swizzled per-wave LDS bounce -> next B frags
      #pragma unroll
      for (int mt = 0; mt < 4; ++mt) {
        float n0 = __builtin_fmaf(__builtin_fmaf(acc[mt][0], rstd, nm), ggr[mt][0], bbr[mt][0]);
        float n1 = __builtin_fmaf(__builtin_fmaf(acc[mt][1], rstd, nm), ggr[mt][1], bbr[mt][1]);
        float n2 = __builtin_fmaf(__builtin_fmaf(acc[mt][2], rstd, nm), ggr[mt][2], bbr[mt][2]);
        float n3 = __builtin_fmaf(__builtin_fmaf(acc[mt][3], rstd, nm), ggr[mt][3], bbr[mt][3]);
        bf16x2 p0 = { (__bf16)n0, (__bf16)n1 };
        bf16x2 p1 = { (__bf16)n2, (__bf16)n3 };
        int di = (b * 32 + 8 * mt + 2 * h) ^ swzD;
        myB[di]     = __builtin_bit_cast(uint32_t, p0);
        myB[di + 1] = __builtin_bit_cast(uint32_t, p1);
      }
      #pragma unroll
      for (int s = 0; s < 2; ++s)
        bfr[s] = *(const u32x4*)(myB + ((b * 32 + 16 * s + 4 * h) ^ swzD));
    }

    // ---- output projection out^T = Wo^T . h3^T + bo ----
    f32x4 ao = aoInit;
    {
      const uint8_t* wp = Wl + 24576 + rowB;
      u32x4 w0 = *(const u32x4*)(wp + ((kOff     ) ^ swzW));
      u32x4 w1 = *(const u32x4*)(wp + ((kOff + 64) ^ swzW));
      ao = __builtin_amdgcn_mfma_f32_16x16x32_bf16(
          __builtin_bit_cast(bf16x8, w0), __builtin_bit_cast(bf16x8, bfr[0]),
          ao, 0, 0, 0);
      ao = __builtin_amdgcn_mfma_f32_16x16x32_bf16(
          __builtin_bit_cast(bf16x8, w1), __builtin_bit_cast(bf16x8, bfr[1]),
          ao, 0, 0, 0);
    }

    // gather 16*5 floats in LDS, store 320B coalesced
    #pragma unroll
    for (int r = 0; r < 4; ++r) {
      int v = 4 * h + r;
      if (v < VOCAB) myF[b * VOCAB + v] = ao[r];
    }
    float* dst = tmp + (size_t)row0 * VOCAB;
    dst[lane] = myF[lane];
    if (lane < 16) dst[64 + lane] = myF[64 + lane];
  }
}

// symmetrize: out[b,i,j,:] = 0.5*(tmp[b,i,j,:] + tmp[b,j,i,:]), LDS tile transpose
__global__ __launch_bounds__(256)
void sym_kernel(const float* __restrict__ tmp, float* __restrict__ out)
{
  __shared__ float A[32][164];
  __shared__ float B[32][164];
  int bid = blockIdx.x;
  int bb = bid / 144, r2 = bid - bb * 144;
  int ti = r2 / 12,  tj = r2 - ti * 12;
  int i0 = ti * 32,  j0 = tj * 32;
  const size_t base = (size_t)bb * SDIM * SDIM;

  for (int idx = threadIdx.x; idx < 32 * 160; idx += 256) {
    int r = idx / 160, c = idx - r * 160;
    A[r][c] = tmp[(base + (size_t)(i0 + r) * SDIM + j0) * VOCAB + c];
    B[r][c] = tmp[(base + (size_t)(j0 + r) * SDIM + i0) * VOCAB + c];
  }
  __syncthreads();
  for (int idx = threadIdx.x; idx < 32 * 160; idx += 256) {
    int r = idx / 160, c = idx - r * 160;
    int jc = c / 5, v = c - jc * 5;
    out[(base + (size_t)(i0 + r) * SDIM + j0) * VOCAB + c] =
        0.5f * (A[r][c] + B[jc][r * 5 + v]);
  }
}

extern "C" void kernel_launch(void* const* d_in, const int* in_sizes, int n_in,
                              void* d_out, int out_size, void* d_ws, size_t ws_size,
                              hipStream_t stream)
{
  const float* x   = (const float*)d_in[0];
  const float* W1  = (const float*)d_in[1];
  const float* b1  = (const float*)d_in[2];
  const float* W2  = (const float*)d_in[3];
  const float* b2  = (const float*)d_in[4];
  const float* W3  = (const float*)d_in[5];
  const float* b3  = (const float*)d_in[6];
  const float* lng = (const float*)d_in[7];
  const float* lnb = (const float*)d_in[8];
  const float* Wo  = (const float*)d_in[9];
  const float* bo  = (const float*)d_in[10];

  float* tmp = (float*)d_ws;   // 23.6 MB scratch
  float* out = (float*)d_out;

  mlp_kernel<<<BLOCKS, 512, 0, stream>>>(x, W1, b1, W2, b2, W3, b3,
                                         lng, lnb, Wo, bo, tmp);
  sym_kernel<<<8 * 12 * 12, 256, 0, stream>>>(tmp, out);
}

// Round 4
// 170.095 us; speedup vs baseline: 3.9261x; 1.2013x over previous
//
#include <hip/hip_runtime.h>
#include <cstdint>
#include <cstddef>

typedef __attribute__((ext_vector_type(8))) __bf16   bf16x8;
typedef __attribute__((ext_vector_type(2))) __bf16   bf16x2;
typedef __attribute__((ext_vector_type(4))) float    f32x4;
typedef __attribute__((ext_vector_type(4))) uint32_t u32x4;
typedef __attribute__((ext_vector_type(2))) uint32_t u32x2;

#define N_ROWS   1179648   // 8*384*384
#define N_TILES  73728     // N_ROWS/16
#define BLOCKS   1024      // 4 waves each -> 4096 waves -> 18 tiles/wave
#define TPW      18        // tiles per wave
#define SDIM     384
#define VOCAB    5

// tanh-form GELU via exp2+rcp: gelu(x) ~= x / (1 + exp2(x*(c1 + c2*x^2)))
// |err vs exact| <= ~4e-4 (fine vs 7.75e-2 threshold)
__device__ __forceinline__ float gelu_fast(float x){
  float u = x * x;
  float w = __builtin_fmaf(-0.10294456f, u, -2.3021255f);
  float e = __builtin_amdgcn_exp2f(x * w);
  return x * __builtin_amdgcn_rcpf(e + 1.0f);
}

__device__ __forceinline__ bf16x8 mk_bf8(f32x4 a, f32x4 b){
  bf16x8 v;
  v[0]=(__bf16)a[0]; v[1]=(__bf16)a[1]; v[2]=(__bf16)a[2]; v[3]=(__bf16)a[3];
  v[4]=(__bf16)b[0]; v[5]=(__bf16)b[1]; v[6]=(__bf16)b[2]; v[7]=(__bf16)b[3];
  return v;
}

// LDS map: [0,24576) W1..W3 bf16 [m][k] swizzled; [24576,26624) Wo^T padded;
//          [26624,27392) b1|b2|b3 as f32.  + per-wave 2KB bounce.
__global__ __launch_bounds__(256)
void mlp_kernel(const float* __restrict__ x,
                const float* __restrict__ W1, const float* __restrict__ b1,
                const float* __restrict__ W2, const float* __restrict__ b2,
                const float* __restrict__ W3, const float* __restrict__ b3,
                const float* __restrict__ lng, const float* __restrict__ lnb,
                const float* __restrict__ Wo,  const float* __restrict__ bo,
                float* __restrict__ tmp)
{
  __shared__ __align__(16) uint8_t  Wl[27392];
  __shared__ __align__(16) uint32_t bounce[4][512];

  const int tid = threadIdx.x;

  // ---- stage weights: fp32 -> LDS bf16 [m][k], swizzle byte^=((m&7)<<4) ----
  {
    int m = tid & 63, g = tid >> 6;          // g in 0..3
    #pragma unroll 1
    for (int idx = g; idx < 96; idx += 4) {  // idx = L*32 + kp
      int L = idx >> 5, kp = idx & 31;
      const float* W = (L == 0) ? W1 : ((L == 1) ? W2 : W3);
      float lo = W[(2 * kp    ) * 64 + m];
      float hi = W[(2 * kp + 1) * 64 + m];
      bf16x2 p = { (__bf16)lo, (__bf16)hi };
      *(uint32_t*)(Wl + L * 8192 + m * 128 + ((4 * kp) ^ ((m & 7) << 4))) =
          __builtin_bit_cast(uint32_t, p);
    }
    int mm = tid & 15;
    #pragma unroll 1
    for (int kp = tid >> 4; kp < 32; kp += 16) {   // Wo^T rows 0..15 (>=5 zero)
      float lo = (mm < VOCAB) ? Wo[(2 * kp    ) * VOCAB + mm] : 0.0f;
      float hi = (mm < VOCAB) ? Wo[(2 * kp + 1) * VOCAB + mm] : 0.0f;
      bf16x2 p = { (__bf16)lo, (__bf16)hi };
      *(uint32_t*)(Wl + 24576 + mm * 128 + ((4 * kp) ^ ((mm & 7) << 4))) =
          __builtin_bit_cast(uint32_t, p);
    }
    if (tid < 192) {                                // biases -> LDS f32
      float v = (tid < 64) ? b1[tid] : ((tid < 128) ? b2[tid - 64] : b3[tid - 128]);
      *(float*)(Wl + 26624 + tid * 4) = v;
    }
  }
  __syncthreads();

  const int wav  = tid >> 6, lane = tid & 63;
  const int h    = lane >> 4;            // k / feature sub-block selector
  const int b    = lane & 15;            // batch-row within 16-row tile
  const int swzW = (b & 7) << 4;         // byte XOR for W-row reads
  const int swzD = (b & 7) << 2;         // dword XOR for bounce buffer
  const int rowB = b * 128;              // W row byte offset
  const int kOff = 16 * h;               // byte offset of k=8h (bf16)
  uint32_t* myB = bounce[wav];
  float*    myF = (float*)bounce[wav];
  const float* biasL = (const float*)(Wl + 26624);

  // ln scale/shift stay in regs (hot path, 32 regs)
  f32x4 ggr[4], bbr[4], aoInit;
  #pragma unroll
  for (int mt = 0; mt < 4; ++mt) {
    ggr[mt] = *(const f32x4*)(lng + 16 * mt + 4 * h);
    bbr[mt] = *(const f32x4*)(lnb + 16 * mt + 4 * h);
  }
  #pragma unroll
  for (int r = 0; r < 4; ++r) {
    int v = 4 * h + r;
    aoInit[r] = (v < VOCAB) ? bo[v] : 0.0f;
  }

  const int gw = blockIdx.x * 4 + wav;   // 0..4095
  int t = gw * TPW;

  // prime x prefetch (tile t)
  f32x4 xr[4];
  {
    const float* px = x + (size_t)(t * 16 + b) * 64 + 8 * h;
    xr[0] = *(const f32x4*)(px);
    xr[1] = *(const f32x4*)(px + 4);
    xr[2] = *(const f32x4*)(px + 32);
    xr[3] = *(const f32x4*)(px + 36);
  }

  #pragma unroll 1
  for (int i = 0; i < TPW; ++i, ++t) {
    // ---- issue next tile's loads early (T14: hide HBM under compute) ----
    f32x4 xn[4];
    {
      int tn = (t + 1 < N_TILES) ? (t + 1) : t;
      const float* pn = x + (size_t)(tn * 16 + b) * 64 + 8 * h;
      xn[0] = *(const f32x4*)(pn);
      xn[1] = *(const f32x4*)(pn + 4);
      xn[2] = *(const f32x4*)(pn + 32);
      xn[3] = *(const f32x4*)(pn + 36);
    }

    u32x4 bfr[2];
    bfr[0] = __builtin_bit_cast(u32x4, mk_bf8(xr[0], xr[1]));
    bfr[1] = __builtin_bit_cast(u32x4, mk_bf8(xr[2], xr[3]));

    // ---- three (Linear -> gelu -> LN) blocks ----
    #pragma unroll
    for (int L = 0; L < 3; ++L) {
      const uint8_t* wp = Wl + L * 8192 + rowB;
      f32x4 acc[4];
      #pragma unroll
      for (int mt = 0; mt < 4; ++mt) {
        u32x4 w0 = *(const u32x4*)(wp + mt * 2048 + ((kOff     ) ^ swzW));
        u32x4 w1 = *(const u32x4*)(wp + mt * 2048 + ((kOff + 64) ^ swzW));
        acc[mt] = *(const f32x4*)(biasL + L * 64 + 16 * mt + 4 * h);  // bias init from LDS
        acc[mt] = __builtin_amdgcn_mfma_f32_16x16x32_bf16(
            __builtin_bit_cast(bf16x8, w0), __builtin_bit_cast(bf16x8, bfr[0]),
            acc[mt], 0, 0, 0);
        acc[mt] = __builtin_amdgcn_mfma_f32_16x16x32_bf16(
            __builtin_bit_cast(bf16x8, w1), __builtin_bit_cast(bf16x8, bfr[1]),
            acc[mt], 0, 0, 0);
      }

      #pragma unroll
      for (int mt = 0; mt < 4; ++mt)
        #pragma unroll
        for (int r = 0; r < 4; ++r)
          acc[mt][r] = gelu_fast(acc[mt][r]);

      // LayerNorm over 64 feats of row b (lanes b, b+16, b+32, b+48)
      float s1 = 0.0f, s2 = 0.0f;
      #pragma unroll
      for (int mt = 0; mt < 4; ++mt)
        #pragma unroll
        for (int r = 0; r < 4; ++r) {
          float v = acc[mt][r];
          s1 += v;
          s2 = __builtin_fmaf(v, v, s2);
        }
      s1 += __shfl_xor(s1, 16); s2 += __shfl_xor(s2, 16);
      s1 += __shfl_xor(s1, 32); s2 += __shfl_xor(s2, 32);
      float mu   = s1 * (1.0f / 64.0f);
      float var  = __builtin_fmaf(s2, (1.0f / 64.0f), -mu * mu);
      float rstd = rsqrtf(var + 1e-5f);
      float nm   = -mu * rstd;

      // normalize + affine -> bf16 -> swizzled LDS bounce (b64) -> next B frags
      #pragma unroll
      for (int mt = 0; mt < 4; ++mt) {
        float n0 = __builtin_fmaf(__builtin_fmaf(acc[mt][0], rstd, nm), ggr[mt][0], bbr[mt][0]);
        float n1 = __builtin_fmaf(__builtin_fmaf(acc[mt][1], rstd, nm), ggr[mt][1], bbr[mt][1]);
        float n2 = __builtin_fmaf(__builtin_fmaf(acc[mt][2], rstd, nm), ggr[mt][2], bbr[mt][2]);
        float n3 = __builtin_fmaf(__builtin_fmaf(acc[mt][3], rstd, nm), ggr[mt][3], bbr[mt][3]);
        bf16x2 p0 = { (__bf16)n0, (__bf16)n1 };
        bf16x2 p1 = { (__bf16)n2, (__bf16)n3 };
        u32x2 pw = { __builtin_bit_cast(uint32_t, p0), __builtin_bit_cast(uint32_t, p1) };
        int di = (b * 32 + 8 * mt + 2 * h) ^ swzD;   // even -> 8B aligned
        *(u32x2*)(myB + di) = pw;
      }
      #pragma unroll
      for (int s = 0; s < 2; ++s)
        bfr[s] = *(const u32x4*)(myB + ((b * 32 + 16 * s + 4 * h) ^ swzD));
    }

    // ---- output projection out^T = Wo^T . h3^T + bo ----
    f32x4 ao = aoInit;
    {
      const uint8_t* wp = Wl + 24576 + rowB;
      u32x4 w0 = *(const u32x4*)(wp + ((kOff     ) ^ swzW));
      u32x4 w1 = *(const u32x4*)(wp + ((kOff + 64) ^ swzW));
      ao = __builtin_amdgcn_mfma_f32_16x16x32_bf16(
          __builtin_bit_cast(bf16x8, w0), __builtin_bit_cast(bf16x8, bfr[0]),
          ao, 0, 0, 0);
      ao = __builtin_amdgcn_mfma_f32_16x16x32_bf16(
          __builtin_bit_cast(bf16x8, w1), __builtin_bit_cast(bf16x8, bfr[1]),
          ao, 0, 0, 0);
    }

    // gather 16*5 floats in LDS, store 320B coalesced
    #pragma unroll
    for (int r = 0; r < 4; ++r) {
      int v = 4 * h + r;
      if (v < VOCAB) myF[b * VOCAB + v] = ao[r];
    }
    float* dst = tmp + (size_t)t * 16 * VOCAB;
    dst[lane] = myF[lane];
    if (lane < 16) dst[64 + lane] = myF[64 + lane];

    xr[0] = xn[0]; xr[1] = xn[1]; xr[2] = xn[2]; xr[3] = xn[3];
  }
}

// symmetrize: out[b,i,j,:] = 0.5*(tmp[b,i,j,:] + tmp[b,j,i,:]), LDS tile transpose
__global__ __launch_bounds__(256)
void sym_kernel(const float* __restrict__ tmp, float* __restrict__ out)
{
  __shared__ float A[32][164];
  __shared__ float B[32][164];
  int bid = blockIdx.x;
  int bb = bid / 144, r2 = bid - bb * 144;
  int ti = r2 / 12,  tj = r2 - ti * 12;
  int i0 = ti * 32,  j0 = tj * 32;
  const size_t base = (size_t)bb * SDIM * SDIM;

  for (int idx = threadIdx.x; idx < 32 * 160; idx += 256) {
    int r = idx / 160, c = idx - r * 160;
    A[r][c] = tmp[(base + (size_t)(i0 + r) * SDIM + j0) * VOCAB + c];
    B[r][c] = tmp[(base + (size_t)(j0 + r) * SDIM + i0) * VOCAB + c];
  }
  __syncthreads();
  for (int idx = threadIdx.x; idx < 32 * 160; idx += 256) {
    int r = idx / 160, c = idx - r * 160;
    int jc = c / 5, v = c - jc * 5;
    out[(base + (size_t)(i0 + r) * SDIM + j0) * VOCAB + c] =
        0.5f * (A[r][c] + B[jc][r * 5 + v]);
  }
}

extern "C" void kernel_launch(void* const* d_in, const int* in_sizes, int n_in,
                              void* d_out, int out_size, void* d_ws, size_t ws_size,
                              hipStream_t stream)
{
  const float* x   = (const float*)d_in[0];
  const float* W1  = (const float*)d_in[1];
  const float* b1  = (const float*)d_in[2];
  const float* W2  = (const float*)d_in[3];
  const float* b2  = (const float*)d_in[4];
  const float* W3  = (const float*)d_in[5];
  const float* b3  = (const float*)d_in[6];
  const float* lng = (const float*)d_in[7];
  const float* lnb = (const float*)d_in[8];
  const float* Wo  = (const float*)d_in[9];
  const float* bo  = (const float*)d_in[10];

  float* tmp = (float*)d_ws;   // 23.6 MB scratch
  float* out = (float*)d_out;

  mlp_kernel<<<BLOCKS, 256, 0, stream>>>(x, W1, b1, W2, b2, W3, b3,
                                         lng, lnb, Wo, bo, tmp);
  sym_kernel<<<8 * 12 * 12, 256, 0, stream>>>(tmp, out);
}